// Round 11
// baseline (53.227 us; speedup 1.0000x reference)
//
#include <hip/hip_runtime.h>
#include <hip/hip_bf16.h>
#include <math.h>

#define H 128
#define NB 8
#define NVN 1024   // virtual nodes per batch
#define MLIG 64    // ligand atoms per batch
#define J 64       // H/2

typedef _Float16 f16;
typedef __attribute__((ext_vector_type(8))) _Float16 f16x8;
typedef __attribute__((ext_vector_type(4))) _Float16 f16x4;
typedef __attribute__((ext_vector_type(4))) float f32x4;

__device__ __forceinline__ f16x8 relu8(f16x8 x) {
    f16x8 z;
    #pragma unroll
    for (int i = 0; i < 8; ++i) z[i] = x[i] > (_Float16)0 ? x[i] : (_Float16)0;
    return z;
}

template <int CTRL>
__device__ __forceinline__ float dpp_add(float x) {
    union { float f; int i; } u, r;
    u.f = x;
    r.i = __builtin_amdgcn_update_dpp(0, u.i, CTRL, 0xf, 0xf, true);
    return x + r.f;
}
__device__ __forceinline__ float row16_sum(float x) {
    x = dpp_add<0xB1>(x);   // xor 1
    x = dpp_add<0x4E>(x);   // xor 2
    x = dpp_add<0x141>(x);  // xor 4 (row_half_mirror)
    x = dpp_add<0x140>(x);  // xor 8 (row_mirror)
    return x;
}

// -------------------------------------------------------------------------
// Kernel 1: direct projection (no combine): v = (VE@Wv+bv)@W1v,
// l = (LE@Wl+bl)@W1l + b1. 16-row tiles, grid 544, f16 out. (R9, passed.)
// -------------------------------------------------------------------------
__global__ __launch_bounds__(256) void project_direct(
    const float* __restrict__ VE, const float* __restrict__ LE,
    const float* __restrict__ Wv, const float* __restrict__ bv,
    const float* __restrict__ Wl, const float* __restrict__ bl,
    const float* __restrict__ W1, const float* __restrict__ b1,
    f16* __restrict__ v_h, f16* __restrict__ l_h)
{
    __shared__ float Xs[16][132];
    __shared__ float Ts[16][132];
    const int bid = blockIdx.x;
    const int tid = threadIdx.x;

    const float* src; const float* Wa; const float* ba; const float* Wb;
    f16* dst; int r0; bool lig;
    if (bid < 512) { src = VE; Wa = Wv; ba = bv; Wb = W1 + H * H;
                     dst = v_h; r0 = bid * 16; lig = false; }
    else           { src = LE; Wa = Wl; ba = bl; Wb = W1;
                     dst = l_h; r0 = (bid - 512) * 16; lig = true; }

    #pragma unroll
    for (int i = 0; i < 2; ++i) {
        int s = tid + i * 256;
        int r = s >> 5, c4 = (s & 31) * 4;
        *(f32x4*)&Xs[r][c4] = *(const f32x4*)&src[(size_t)(r0 + r) * H + c4];
    }
    __syncthreads();

    const int rt = (tid >> 5) * 2;
    const int c0 = (tid & 31) * 4;

    f32x4 a0 = *(const f32x4*)&ba[c0];
    f32x4 a1 = a0;
    #pragma unroll 4
    for (int k4 = 0; k4 < 32; ++k4) {
        f32x4 x0 = *(const f32x4*)&Xs[rt][k4 * 4];
        f32x4 x1 = *(const f32x4*)&Xs[rt + 1][k4 * 4];
        f32x4 w0 = *(const f32x4*)&Wa[(size_t)(k4 * 4 + 0) * H + c0];
        f32x4 w1 = *(const f32x4*)&Wa[(size_t)(k4 * 4 + 1) * H + c0];
        f32x4 w2 = *(const f32x4*)&Wa[(size_t)(k4 * 4 + 2) * H + c0];
        f32x4 w3 = *(const f32x4*)&Wa[(size_t)(k4 * 4 + 3) * H + c0];
        a0 += x0[0] * w0; a0 += x0[1] * w1; a0 += x0[2] * w2; a0 += x0[3] * w3;
        a1 += x1[0] * w0; a1 += x1[1] * w1; a1 += x1[2] * w2; a1 += x1[3] * w3;
    }
    *(f32x4*)&Ts[rt][c0]     = a0;
    *(f32x4*)&Ts[rt + 1][c0] = a1;
    __syncthreads();

    f32x4 b0;
    if (lig) b0 = *(const f32x4*)&b1[c0];
    else     b0 = (f32x4){0.f, 0.f, 0.f, 0.f};
    f32x4 b1a = b0;
    #pragma unroll 4
    for (int k4 = 0; k4 < 32; ++k4) {
        f32x4 x0 = *(const f32x4*)&Ts[rt][k4 * 4];
        f32x4 x1 = *(const f32x4*)&Ts[rt + 1][k4 * 4];
        f32x4 w0 = *(const f32x4*)&Wb[(size_t)(k4 * 4 + 0) * H + c0];
        f32x4 w1 = *(const f32x4*)&Wb[(size_t)(k4 * 4 + 1) * H + c0];
        f32x4 w2 = *(const f32x4*)&Wb[(size_t)(k4 * 4 + 2) * H + c0];
        f32x4 w3 = *(const f32x4*)&Wb[(size_t)(k4 * 4 + 3) * H + c0];
        b0  += x0[0] * w0; b0  += x0[1] * w1; b0  += x0[2] * w2; b0  += x0[3] * w3;
        b1a += x1[0] * w0; b1a += x1[1] * w1; b1a += x1[2] * w2; b1a += x1[3] * w3;
    }

    f16x4 h0, h1;
    #pragma unroll
    for (int i = 0; i < 4; ++i) { h0[i] = (f16)b0[i]; h1[i] = (f16)b1a[i]; }
    *(f16x4*)&dst[(size_t)(r0 + rt) * H + c0]     = h0;
    *(f16x4*)&dst[(size_t)(r0 + rt + 1) * H + c0] = h1;
}

// -------------------------------------------------------------------------
// Kernel 2: pairwise MLP -> z, DIRECT-LOAD version: no LDS, no barriers.
// Grid 512 (one bm per block, XCD-swizzled so each XCD reads only its
// batch's 256 KB L2-resident v_h slice), 256 thr = 4 waves. Wave wl owns
// n-rows [wl*256, wl*256+256) as 16 fragments of 16 rows; per fragment,
// each lane (g,c) loads its A-slice straight from L2 (16B dwordx4; a
// wave's 64 lanes cover 16 rows x 64 B contiguous per ks -> no overfetch
// across the 4-ks loop). One-fragment-ahead prefetch; waves fully
// independent -> latency hidden by ILP + free wave drift.
// -------------------------------------------------------------------------
__global__ __launch_bounds__(256) void pair_z_direct(
    const f16* __restrict__ v_h, const f16* __restrict__ l_h,
    const float* __restrict__ W2, const float* __restrict__ b2,
    const float* __restrict__ W3, float* __restrict__ zbuf)
{
    const int bid = blockIdx.x;
    const int bm  = (bid & 7) * 64 + (bid >> 3);   // XCD swizzle, bijective
    const int b   = bm >> 6;

    const int tid  = threadIdx.x;
    const int wl   = tid >> 6;         // wave 0..3 -> n-quarter
    const int lane = tid & 63;
    const int g    = lane >> 4;
    const int c    = lane & 15;

    // W2 as f16 B-fragments in registers
    f16x8 bw[4][4];
    #pragma unroll
    for (int ks = 0; ks < 4; ++ks)
        #pragma unroll
        for (int fj = 0; fj < 4; ++fj) {
            f16x8 f;
            #pragma unroll
            for (int e = 0; e < 8; ++e)
                f[e] = (f16)W2[(ks * 32 + g * 8 + e) * J + fj * 16 + c];
            bw[ks][fj] = f;
        }

    f16x8 lp[4];
    #pragma unroll
    for (int ks = 0; ks < 4; ++ks)
        lp[ks] = *(const f16x8*)&l_h[(size_t)bm * H + ks * 32 + g * 8];

    float b2r[4], w3r[4];
    #pragma unroll
    for (int fj = 0; fj < 4; ++fj) {
        b2r[fj] = b2[fj * 16 + c];
        w3r[fj] = W3[fj * 16 + c];
    }

    // lane's A-row base: row = b*NVN + wl*256 + c (+ f*16 per fragment)
    const f16* vbase = v_h + ((size_t)b * NVN + wl * 256 + c) * H + g * 8;
    float* zdst = zbuf + (size_t)bm * NVN + wl * 256;

    // prefetch fragment 0
    f16x8 cur[4], nxt[4];
    #pragma unroll
    for (int ks = 0; ks < 4; ++ks)
        cur[ks] = *(const f16x8*)(vbase + ks * 32);

    #pragma unroll 2
    for (int f = 0; f < 16; ++f) {
        if (f < 15) {                   // issue next fragment's loads early
            const f16* p = vbase + (size_t)(f + 1) * 16 * H;
            #pragma unroll
            for (int ks = 0; ks < 4; ++ks)
                nxt[ks] = *(const f16x8*)(p + ks * 32);
        }

        f32x4 acc[4];
        #pragma unroll
        for (int fj = 0; fj < 4; ++fj) acc[fj] = (f32x4){0.f, 0.f, 0.f, 0.f};

        #pragma unroll
        for (int ks = 0; ks < 4; ++ks) {
            f16x8 af = relu8(cur[ks] + lp[ks]);
            #pragma unroll
            for (int fj = 0; fj < 4; ++fj)
                acc[fj] = __builtin_amdgcn_mfma_f32_16x16x32_f16(
                    af, bw[ks][fj], acc[fj], 0, 0, 0);
        }

        // layer 3: z[n] = sum_j relu(acc + b2[j]) * W3[j]; DPP 16-lane reduce
        float pz[4];
        #pragma unroll
        for (int r = 0; r < 4; ++r) {
            float s = fmaxf(acc[0][r] + b2r[0], 0.f) * w3r[0]
                    + fmaxf(acc[1][r] + b2r[1], 0.f) * w3r[1]
                    + fmaxf(acc[2][r] + b2r[2], 0.f) * w3r[2]
                    + fmaxf(acc[3][r] + b2r[3], 0.f) * w3r[3];
            pz[r] = row16_sum(s);
        }
        if (c < 4) {
            float zv = (c == 0) ? pz[0] : (c == 1) ? pz[1] : (c == 2) ? pz[2] : pz[3];
            zdst[f * 16 + g * 4 + c] = zv;
        }

        #pragma unroll
        for (int ks = 0; ks < 4; ++ks) cur[ks] = nxt[ks];
    }
}

// -------------------------------------------------------------------------
// Kernel 3: per-(b,m) softmax over z + attn write + coords einsum.
// -------------------------------------------------------------------------
__global__ __launch_bounds__(256) void softmax_coords(
    const float* __restrict__ zbuf, const float* __restrict__ vc,
    float* __restrict__ out_coords, float* __restrict__ out_attn)
{
    __shared__ float red[4];
    __shared__ float redc[3][4];

    const int tid = threadIdx.x;
    const int bm  = blockIdx.x;
    const int b   = bm >> 6;
    const int wid = tid >> 6, lane = tid & 63;

    float zloc[4];
    float mx = -INFINITY;
    #pragma unroll
    for (int k = 0; k < 4; ++k) {
        zloc[k] = zbuf[(size_t)bm * NVN + tid + k * 256];
        mx = fmaxf(mx, zloc[k]);
    }
    #pragma unroll
    for (int off = 32; off > 0; off >>= 1) mx = fmaxf(mx, __shfl_xor(mx, off));
    if (lane == 0) red[wid] = mx;
    __syncthreads();
    if (tid == 0)
        red[0] = fmaxf(fmaxf(red[0], red[1]), fmaxf(red[2], red[3]));
    __syncthreads();
    const float gmax = red[0];
    __syncthreads();

    float s = 0.f;
    #pragma unroll
    for (int k = 0; k < 4; ++k) {
        zloc[k] = expf(zloc[k] - gmax);
        s += zloc[k];
    }
    #pragma unroll
    for (int off = 32; off > 0; off >>= 1) s += __shfl_xor(s, off);
    if (lane == 0) red[wid] = s;
    __syncthreads();
    if (tid == 0) red[0] = red[0] + red[1] + red[2] + red[3];
    __syncthreads();
    const float inv = 1.f / red[0];

    float cx = 0.f, cy = 0.f, cz = 0.f;
    #pragma unroll
    for (int k = 0; k < 4; ++k) {
        int n = tid + k * 256;
        float a = zloc[k] * inv;
        out_attn[(size_t)bm * NVN + n] = a;
        const float* vcp = vc + (size_t)(b * NVN + n) * 3;
        cx += a * vcp[0];
        cy += a * vcp[1];
        cz += a * vcp[2];
    }
    #pragma unroll
    for (int off = 32; off > 0; off >>= 1) {
        cx += __shfl_xor(cx, off);
        cy += __shfl_xor(cy, off);
        cz += __shfl_xor(cz, off);
    }
    if (lane == 0) { redc[0][wid] = cx; redc[1][wid] = cy; redc[2][wid] = cz; }
    __syncthreads();
    if (tid == 0) {
        out_coords[bm * 3 + 0] = redc[0][0] + redc[0][1] + redc[0][2] + redc[0][3];
        out_coords[bm * 3 + 1] = redc[1][0] + redc[1][1] + redc[1][2] + redc[1][3];
        out_coords[bm * 3 + 2] = redc[2][0] + redc[2][1] + redc[2][2] + redc[2][3];
    }
}

// -------------------------------------------------------------------------
extern "C" void kernel_launch(void* const* d_in, const int* in_sizes, int n_in,
                              void* d_out, int out_size, void* d_ws, size_t ws_size,
                              hipStream_t stream)
{
    const float* VE = (const float*)d_in[0];   // [8192, 128]
    const float* vc = (const float*)d_in[1];   // [8192, 3]
    const float* LE = (const float*)d_in[2];   // [512, 128]
    const float* Wv = (const float*)d_in[6];
    const float* bv = (const float*)d_in[7];
    const float* Wl = (const float*)d_in[8];
    const float* bl = (const float*)d_in[9];
    const float* W1 = (const float*)d_in[10];
    const float* b1 = (const float*)d_in[11];
    const float* W2 = (const float*)d_in[12];
    const float* b2 = (const float*)d_in[13];
    const float* W3 = (const float*)d_in[14];
    // b3 cancels in softmax

    float* ws   = (float*)d_ws;
    f16*   v_hp = (f16*)ws;                        // 8192*128 f16 = 2 MB
    f16*   l_hp = v_hp + (size_t)NB * NVN * H;     // 512*128 f16
    float* zbuf = (float*)(l_hp + (size_t)NB * MLIG * H);  // 512*1024 fp32

    float* out_coords = (float*)d_out;             // [512, 3]
    float* out_attn   = out_coords + NB * MLIG * 3;

    project_direct<<<544, 256, 0, stream>>>(
        VE, LE, Wv, bv, Wl, bl, W1, b1, v_hp, l_hp);

    pair_z_direct<<<512, 256, 0, stream>>>(
        v_hp, l_hp, W2, b2, W3, zbuf);

    softmax_coords<<<NB * MLIG, 256, 0, stream>>>(
        zbuf, vc, out_coords, out_attn);
}